// Round 6
// baseline (229.636 us; speedup 1.0000x reference)
//
#include <hip/hip_runtime.h>
#include <hip/hip_bf16.h>

#define NNZ 131072
#define MT  1048576
#define EMB 128
#define NSEG 512            // segments = high 9 bits of io

typedef __attribute__((ext_vector_type(8))) short  short8;
typedef __attribute__((ext_vector_type(4))) float  floatx4;

__device__ __forceinline__ ushort f2bf(float f) {
    unsigned u = __float_as_uint(f);
    u = (u + 0x7FFFu + ((u >> 16) & 1u)) >> 16;   // RNE
    return (ushort)u;
}
__device__ __forceinline__ float bfl(unsigned u) { return __uint_as_float(u << 16); }
__device__ __forceinline__ float bfh(unsigned u) { return __uint_as_float(u & 0xffff0000u); }

// ---------------------------------------------------------------------------
// prep: blocks 0..31 pack weights into B-fragment order; blocks 32..287 build
// per-block 512-bin histograms of io>>8 (4096 elements each, LDS atomics only).
// Block 32 also inits the pairs pad and ptr[NNZ].
// ---------------------------------------------------------------------------
__global__ __launch_bounds__(256) void prep_kernel(
    const float* __restrict__ W10, const float* __restrict__ W11,
    const float* __restrict__ W20, const float* __restrict__ W21,
    ushort* __restrict__ Wpk, const int* __restrict__ io,
    int* __restrict__ bh, int2* __restrict__ pairs, int* __restrict__ ptr)
{
    __shared__ int h[512];
    const int bid = blockIdx.x, tid = threadIdx.x;

    if (bid < 32) {                          // ---- weight pack ----
        int s = bid * 256 + tid;             // 0..8191
        int L = s >> 11, sl = s & 2047;
        const float* W = (L == 0) ? W10 : (L == 1) ? W11 : (L == 2) ? W20 : W21;
        int lane = sl & 63, nk = sl >> 6;
        int col  = (nk >> 2) * 16 + (lane & 15);
        int krow = (nk & 3) * 32 + (lane >> 4) * 8;
        short8 w;
        #pragma unroll
        for (int j = 0; j < 8; ++j)
            w[j] = (short)f2bf(W[(krow + j) * EMB + col]);
        *(short8*)&Wpk[(size_t)s * 8] = w;
        return;
    }

    const int b = bid - 32;                  // 0..255
    if (b == 0) {
        if (tid < 16) pairs[MT + tid] = make_int2(0, 0);
        if (tid == 16) ptr[NNZ] = MT;
    }
    for (int i = tid; i < 512; i += 256) h[i] = 0;
    __syncthreads();
    const int4* io4 = (const int4*)io + b * 1024;
    for (int j = tid; j < 1024; j += 256) {
        int4 v = io4[j];
        atomicAdd(&h[v.x >> 8], 1);
        atomicAdd(&h[v.y >> 8], 1);
        atomicAdd(&h[v.z >> 8], 1);
        atomicAdd(&h[v.w >> 8], 1);
    }
    __syncthreads();
    for (int d = tid; d < 512; d += 256) bh[d * 256 + b] = h[d];
}

// ---------------------------------------------------------------------------
// scan1: exclusive scan of bh[131072] (digit-major) in place; also writes
// segptr[d] (segment bases at flat index d*256) and segptr[512]=MT.
// ---------------------------------------------------------------------------
__global__ __launch_bounds__(1024) void scan1_kernel(
    int* __restrict__ bh, int* __restrict__ segptr)
{
    __shared__ int part[1024];
    int tid = threadIdx.x;
    int4* c4 = (int4*)(bh + tid * 128);
    int s = 0;
    #pragma unroll 8
    for (int j = 0; j < 32; ++j) { int4 v = c4[j]; s += v.x + v.y + v.z + v.w; }
    part[tid] = s;
    __syncthreads();
    for (int off = 1; off < 1024; off <<= 1) {
        int v = (tid >= off) ? part[tid - off] : 0;
        __syncthreads();
        part[tid] += v;
        __syncthreads();
    }
    int run = part[tid] - s;                 // exclusive prefix at tid*128
    if ((tid & 1) == 0) segptr[tid >> 1] = run;
    if (tid == 1023) segptr[NSEG] = run + s; // = MT
    #pragma unroll 8
    for (int j = 0; j < 32; ++j) {
        int4 v = c4[j]; int4 w;
        w.x = run; run += v.x;
        w.y = run; run += v.y;
        w.z = run; run += v.z;
        w.w = run; run += v.w;
        c4[j] = w;
    }
}

// ---------------------------------------------------------------------------
// seg_scatter: block b claims ranks in LDS from its precomputed disjoint
// bases, writes packed (low8<<34 | b17<<17 | a17) u64s grouped by segment.
// Zero global atomics.
// ---------------------------------------------------------------------------
__global__ __launch_bounds__(256) void seg_scatter_kernel(
    const int* __restrict__ io, const int* __restrict__ ia,
    const int* __restrict__ ib, const int* __restrict__ bh,
    unsigned long long* __restrict__ srt)
{
    __shared__ int cur[512];
    const int b = blockIdx.x, tid = threadIdx.x;
    for (int d = tid; d < 512; d += 256) cur[d] = bh[d * 256 + b];
    __syncthreads();
    const int4* io4 = (const int4*)io + b * 1024;
    const int4* ia4 = (const int4*)ia + b * 1024;
    const int4* ib4 = (const int4*)ib + b * 1024;
    for (int j = tid; j < 1024; j += 256) {
        int4 o = io4[j], a = ia4[j], c = ib4[j];
        int p;
        p = atomicAdd(&cur[o.x >> 8], 1);
        srt[p] = (unsigned long long)(unsigned)a.x |
                 ((unsigned long long)(unsigned)c.x << 17) |
                 ((unsigned long long)(unsigned)(o.x & 255) << 34);
        p = atomicAdd(&cur[o.y >> 8], 1);
        srt[p] = (unsigned long long)(unsigned)a.y |
                 ((unsigned long long)(unsigned)c.y << 17) |
                 ((unsigned long long)(unsigned)(o.y & 255) << 34);
        p = atomicAdd(&cur[o.z >> 8], 1);
        srt[p] = (unsigned long long)(unsigned)a.z |
                 ((unsigned long long)(unsigned)c.z << 17) |
                 ((unsigned long long)(unsigned)(o.z & 255) << 34);
        p = atomicAdd(&cur[o.w >> 8], 1);
        srt[p] = (unsigned long long)(unsigned)a.w |
                 ((unsigned long long)(unsigned)c.w << 17) |
                 ((unsigned long long)(unsigned)(o.w & 255) << 34);
    }
}

// ---------------------------------------------------------------------------
// seg_sort: one block per segment. LDS 256-bin counting sort of the segment
// (two passes over srt, no element staging -> any segment size). Writes
// pairs[] in exact CSR order and ptr[] for its 256 buckets.
// ---------------------------------------------------------------------------
__global__ __launch_bounds__(256) void seg_sort_kernel(
    const unsigned long long* __restrict__ srt, const int* __restrict__ segptr,
    int2* __restrict__ pairs, int* __restrict__ ptr)
{
    __shared__ int h[256];
    __shared__ int sc[256];
    const int s = blockIdx.x, tid = threadIdx.x;
    const int beg = segptr[s], end = segptr[s + 1];

    h[tid] = 0;
    __syncthreads();
    for (int i = beg + tid; i < end; i += 256)
        atomicAdd(&h[(int)(srt[i] >> 34)], 1);
    __syncthreads();
    sc[tid] = h[tid];
    __syncthreads();
    for (int off = 1; off < 256; off <<= 1) {
        int v = (tid >= off) ? sc[tid - off] : 0;
        __syncthreads();
        sc[tid] += v;
        __syncthreads();
    }
    int base = beg + sc[tid] - h[tid];       // exclusive prefix + segment base
    ptr[(s << 8) + tid] = base;
    __syncthreads();
    h[tid] = base;                           // reuse h as claim counters
    __syncthreads();
    for (int i = beg + tid; i < end; i += 256) {
        unsigned long long v = srt[i];
        int p = atomicAdd(&h[(int)(v >> 34)], 1);
        pairs[p] = make_int2((int)(v & 0x1FFFF), (int)((v >> 17) & 0x1FFFF));
    }
}

// ---------------------------------------------------------------------------
// MLP: 256 thr (4 waves), 64 rows/block, grid 2048, 3 blocks/CU (proven ~31us)
// ---------------------------------------------------------------------------
__global__ __launch_bounds__(256, 3) void mlp_kernel(
    const float* __restrict__ Xv, const ushort* __restrict__ Wpk,
    const float* __restrict__ b10, const float* __restrict__ b11,
    const float* __restrict__ b20, const float* __restrict__ b21,
    ushort* __restrict__ X1b, ushort* __restrict__ X2b)
{
    __shared__ ushort Wp[16384];
    __shared__ ushort Hs[8192];

    const int tid  = threadIdx.x;
    const int wave = tid >> 6;
    const int lane = tid & 63;
    const int g    = lane >> 4;
    const int r    = lane & 15;
    const int rowbase = blockIdx.x * 64 + wave * 16;
    char* hw = (char*)(Hs + wave * 2048);

    short8 af[4];
    {
        const float* xsrc = Xv + (size_t)(rowbase + r) * EMB;
        #pragma unroll
        for (int kt = 0; kt < 4; ++kt) {
            const float4* p = (const float4*)(xsrc + kt * 32 + g * 8);
            float4 v0 = p[0], v1 = p[1];
            short8 a;
            a[0] = (short)f2bf(v0.x); a[1] = (short)f2bf(v0.y);
            a[2] = (short)f2bf(v0.z); a[3] = (short)f2bf(v0.w);
            a[4] = (short)f2bf(v1.x); a[5] = (short)f2bf(v1.y);
            a[6] = (short)f2bf(v1.z); a[7] = (short)f2bf(v1.w);
            af[kt] = a;
        }
    }

    auto stageW = [&](int L) {
        const ushort* src = Wpk + (size_t)L * 16384;
        #pragma unroll
        for (int s = tid; s < 2048; s += 256)
            *(short8*)&Wp[s * 8] = *(const short8*)&src[(size_t)s * 8];
    };

    floatx4 acc[8];
    auto runMFMA = [&](const short8* a4) {
        #pragma unroll
        for (int n = 0; n < 8; ++n) {
            floatx4 c = {0.f, 0.f, 0.f, 0.f};
            #pragma unroll
            for (int kt = 0; kt < 4; ++kt) {
                short8 b = *(const short8*)&Wp[((n * 4 + kt) * 64 + lane) * 8];
                c = __builtin_amdgcn_mfma_f32_16x16x32_bf16(b, a4[kt], c, 0, 0, 0);
            }
            acc[n] = c;
        }
    };

    auto epi = [&](const float* __restrict__ bias) {
        #pragma unroll
        for (int n = 0; n < 8; ++n) {
            float4 bv = *(const float4*)&bias[n * 16 + g * 4];
            ushort4 w;
            w.x = f2bf(fmaxf(acc[n][0] + bv.x, 0.f));
            w.y = f2bf(fmaxf(acc[n][1] + bv.y, 0.f));
            w.z = f2bf(fmaxf(acc[n][2] + bv.z, 0.f));
            w.w = f2bf(fmaxf(acc[n][3] + bv.w, 0.f));
            int byte = r * 256 + n * 32 + g * 8;
            byte ^= ((r & 3) << 5) ^ ((r & 4) << 2);
            *(ushort4*)(hw + byte) = w;
        }
    };

    auto loadH = [&](short8* h4) {
        #pragma unroll
        for (int kt = 0; kt < 4; ++kt) {
            int byte = r * 256 + kt * 64 + g * 16;
            byte ^= ((r & 3) << 5) ^ ((r & 4) << 2);
            h4[kt] = *(const short8*)(hw + byte);
        }
    };

    auto storeG = [&](ushort* __restrict__ dst) {
        #pragma unroll
        for (int it = 0; it < 4; ++it) {
            int row  = it * 4 + g;
            int byte = row * 256 + (lane & 15) * 16;
            byte ^= ((row & 3) << 5) ^ ((row & 4) << 2);
            short8 v = *(const short8*)(hw + byte);
            *(short8*)&dst[(size_t)rowbase * EMB + row * EMB + (lane & 15) * 8] = v;
        }
    };

    short8 h4[4];

    stageW(0); __syncthreads();
    runMFMA(af); epi(b10); __syncthreads();
    stageW(1); loadH(h4); __syncthreads();
    runMFMA(h4); epi(b11); __syncthreads();
    stageW(2); storeG(X1b); __syncthreads();
    runMFMA(af); epi(b20); __syncthreads();
    stageW(3); loadH(h4); __syncthreads();
    runMFMA(h4); epi(b21); __syncthreads();
    storeG(X2b);
}

// ---------------------------------------------------------------------------
// Gather (CSR): one wave per output row; 16 entries all in flight with
// operand-zero masking; rare tail loop for n>16.
// ---------------------------------------------------------------------------
__global__ __launch_bounds__(256) void gather_kernel(
    const ushort* __restrict__ X1b, const ushort* __restrict__ X2b,
    const int2* __restrict__ pairs, const int* __restrict__ ptr,
    float* __restrict__ out)
{
    int o    = blockIdx.x * 4 + (threadIdx.x >> 6);
    int lane = threadIdx.x & 63;
    int beg = ptr[o], end = ptr[o + 1];
    int n = end - beg;
    const unsigned* x1 = (const unsigned*)X1b + lane;
    const unsigned* x2 = (const unsigned*)X2b + lane;

    int2 P[16];
    #pragma unroll
    for (int e = 0; e < 16; ++e) P[e] = pairs[beg + (e < n ? e : 0)];

    float ax = 0.f, ay = 0.f;
    #pragma unroll
    for (int e = 0; e < 16; ++e) {
        unsigned u1 = x1[(unsigned)P[e].x * 64u];
        unsigned u2 = x2[(unsigned)P[e].y * 64u];
        if (e >= n) u1 = 0u;
        ax += bfl(u1) * bfl(u2);
        ay += bfh(u1) * bfh(u2);
    }
    if (n > 16) {                            // uniform, ~0.3% of rows
        for (int i = beg + 16; i < end; ++i) {
            int2 p = pairs[i];
            unsigned u1 = x1[(unsigned)p.x * 64u];
            unsigned u2 = x2[(unsigned)p.y * 64u];
            ax += bfl(u1) * bfl(u2);
            ay += bfh(u1) * bfh(u2);
        }
    }
    *(float2*)(out + (size_t)o * EMB + lane * 2) = make_float2(ax, ay);
}

// ---------------------------------------------------------------------------
extern "C" void kernel_launch(void* const* d_in, const int* in_sizes, int n_in,
                              void* d_out, int out_size, void* d_ws, size_t ws_size,
                              hipStream_t stream)
{
    (void)in_sizes; (void)n_in; (void)out_size; (void)ws_size;

    const float* Xv  = (const float*)d_in[0];
    const float* W10 = (const float*)d_in[1];
    const float* b10 = (const float*)d_in[2];
    const float* W11 = (const float*)d_in[3];
    const float* b11 = (const float*)d_in[4];
    const float* W20 = (const float*)d_in[5];
    const float* b20 = (const float*)d_in[6];
    const float* W21 = (const float*)d_in[7];
    const float* b21 = (const float*)d_in[8];
    const int*   ia  = (const int*)d_in[9];
    const int*   ib  = (const int*)d_in[10];
    const int*   io  = (const int*)d_in[11];
    float* out = (float*)d_out;

    char* ws = (char*)d_ws;
    ushort*             X1b   = (ushort*)(ws);                  // 32 MB
    ushort*             X2b   = (ushort*)(ws + 33554432);       // 32 MB
    ushort*             Wpk   = (ushort*)(ws + 67108864);       // 256 KB
    int*                bh    = (int*)(ws + 67371008);          // 512 KB
    int*                segptr= (int*)(ws + 67895296);          // 4 KB
    int*                ptr   = (int*)(ws + 67899392);          // 513 KB
    unsigned long long* srt   = (unsigned long long*)(ws + 68423936);   // 8 MB
    int2*               pairs = (int2*)(ws + 76812544);         // 8 MB + pad

    prep_kernel<<<288, 256, 0, stream>>>(W10, W11, W20, W21, Wpk, io,
                                         bh, pairs, ptr);
    mlp_kernel<<<2048, 256, 0, stream>>>(Xv, Wpk, b10, b11, b20, b21,
                                         X1b, X2b);
    scan1_kernel<<<1, 1024, 0, stream>>>(bh, segptr);
    seg_scatter_kernel<<<256, 256, 0, stream>>>(io, ia, ib, bh, srt);
    seg_sort_kernel<<<NSEG, 256, 0, stream>>>(srt, segptr, pairs, ptr);
    gather_kernel<<<NNZ / 4, 256, 0, stream>>>(X1b, X2b, pairs, ptr, out);
}